// Round 11
// baseline (417.515 us; speedup 1.0000x reference)
//
#include <hip/hip_runtime.h>
#include <stdint.h>

#define B_   256
#define NPG  512
#define NG   131072
#define EPG  4096
#define NQPG 16
#define NQ   4096
#define EQPG 128
#define L_   2

typedef __attribute__((ext_vector_type(8))) short short8;
typedef __attribute__((ext_vector_type(4))) float floatx4;

__device__ inline float bf2f(unsigned short u){
    union { unsigned int i; float f; } x; x.i = ((unsigned int)u) << 16; return x.f;
}
__device__ inline unsigned short f2bf(float f){
    union { float f; unsigned int i; } x; x.f = f;
    unsigned int r = x.i + 0x7fff + ((x.i >> 16) & 1);  // RNE
    return (unsigned short)(r >> 16);
}
__device__ inline float d2(unsigned int a, unsigned int b, float c){
#if __has_builtin(__builtin_amdgcn_fdot2_f32_bf16)
    typedef __attribute__((ext_vector_type(2))) __bf16 bf16x2;
    union { unsigned int u; bf16x2 v; } xa, xb;
    xa.u = a; xb.u = b;
    return __builtin_amdgcn_fdot2_f32_bf16(xa.v, xb.v, c, false);
#else
    union { unsigned int u; float f; } la, ha, lb, hb;
    la.u = a << 16; ha.u = a & 0xffff0000u;
    lb.u = b << 16; hb.u = b & 0xffff0000u;
    return fmaf(la.f, lb.f, fmaf(ha.f, hb.f, c));
#endif
}
__device__ inline float dot8(uint4 a, uint4 b){
    return d2(a.x,b.x, d2(a.y,b.y, d2(a.z,b.z, d2(a.w,b.w, 0.f))));
}

// ---- transpose weights (fp32 in) to [N][K] bf16 ----
__global__ void k_transpose(const float* Wg, const float* Wq,
                            const float* W1r, const float* W2r,
                            unsigned short* WgT, unsigned short* WqT,
                            unsigned short* W1aT, unsigned short* W2rT){
    int idx = blockIdx.x*256 + threadIdx.x;
    if (idx < 8192){
        int k = idx >> 7, n = idx & 127; WgT[n*64 + k] = f2bf(Wg[idx]);
    } else if (idx < 16384){
        int i = idx - 8192; int k = i>>7, n = i&127; WqT[n*64+k] = f2bf(Wq[i]);
    } else if (idx < 49152){
        int i = idx - 16384; int l = i >> 14; int j = i & 16383; int k = j>>7, n = j&127;
        W1aT[l*16384 + n*128 + k] = f2bf(W1r[l*32768 + j]);
    } else {
        int i = idx - 49152; int l = i >> 14; int j = i & 16383; int k = j>>7, n = j&127;
        W2rT[l*16384 + n*128 + k] = f2bf(W2r[i]);
    }
}

// ---- one-shot CSR build: csr-ordered src/dst arrays + offsets + degf ----
__global__ __launch_bounds__(256) void k_csr(const int* __restrict__ g_src,
        const int* __restrict__ g_dst,
        unsigned short* __restrict__ csrc_g, unsigned short* __restrict__ cdst_g,
        int* __restrict__ off_g, float* __restrict__ degf){
    int g = blockIdx.x, t = threadIdx.x, lane = t & 63;
    __shared__ int cnt[NPG], woff[NPG];
    __shared__ int gscan[64];
    int gbase = g*NPG; size_t ebase = (size_t)g*EPG;
    for (int n=t;n<NPG;n+=256) cnt[n]=0;
    __syncthreads();
    for (int i=t;i<EPG;i+=256){
        int d = g_dst[ebase+i]-gbase;
        atomicAdd(&cnt[d],1);
    }
    __syncthreads();
    if (t < 64){
        int s=0;
        #pragma unroll
        for (int j=0;j<8;j++) s += cnt[t*8+j];
        int v=s;
        #pragma unroll
        for (int o=1;o<64;o<<=1){ int u=__shfl_up(v,o); if (lane>=o) v+=u; }
        gscan[t]=v;
    }
    __syncthreads();
    for (int n=t;n<NPG;n+=256){
        int grp=n>>3; int base = grp?gscan[grp-1]:0;
        for (int j=grp*8;j<n;j++) base+=cnt[j];
        off_g[g*NPG+n]=base; woff[n]=base;
        degf[gbase+n] = cnt[n]>0 ? 1.f : 0.f;
    }
    __syncthreads();
    for (int i=t;i<EPG;i+=256){
        int s = g_src[ebase+i]-gbase;
        int d = g_dst[ebase+i]-gbase;
        int pos = atomicAdd(&woff[d],1);
        csrc_g[ebase+pos]=(unsigned short)s;
        cdst_g[ebase+pos]=(unsigned short)d;
    }
}

// ---- proj: out_bf16[M,128] = A_f32[M,64] @ WtT + bias ; optional row sumsq ----
__global__ __launch_bounds__(256) void k_proj(const float* __restrict__ A,
        const unsigned short* __restrict__ Wt, const float* __restrict__ bias,
        unsigned short* __restrict__ out, float* __restrict__ nrm2){
    const int K = 64;
    int wave = threadIdx.x >> 6, lane = threadIdx.x & 63;
    int quad = lane >> 4, l16 = lane & 15;
    int wrow = blockIdx.x*64 + wave*16;
    floatx4 acc[8];
    #pragma unroll
    for (int t=0;t<8;t++){
        #pragma unroll
        for (int r=0;r<4;r++) acc[t][r]=0.f;
    }
    #pragma unroll
    for (int ks = 0; ks < 2; ks++){
        int koff = ks*32 + quad*8;
        const float* ap = A + (size_t)(wrow+l16)*K + koff;
        short8 a;
        #pragma unroll
        for (int j=0;j<8;j++) a[j] = (short)f2bf(ap[j]);
        #pragma unroll
        for (int t=0;t<8;t++){
            short8 b = *(const short8*)(Wt + (size_t)(t*16+l16)*K + koff);
            acc[t] = __builtin_amdgcn_mfma_f32_16x16x32_bf16(a, b, acc[t], 0,0,0);
        }
    }
    float ss[4] = {0.f,0.f,0.f,0.f};
    #pragma unroll
    for (int t=0;t<8;t++){
        int col = t*16 + l16;
        float bv = bias[col];
        #pragma unroll
        for (int r=0;r<4;r++){
            float v = acc[t][r] + bv;
            out[(size_t)(wrow + quad*4 + r)*128 + col] = f2bf(v);
            ss[r] += v*v;
        }
    }
    if (nrm2){
        #pragma unroll
        for (int r=0;r<4;r++){
            #pragma unroll
            for (int o=1;o<16;o<<=1) ss[r] += __shfl_xor(ss[r], o);
        }
        if (l16==0){
            #pragma unroll
            for (int r=0;r<4;r++) nrm2[wrow + quad*4 + r] = ss[r];
        }
    }
}

// ---- query AGNN + Qg + fused cg2 = hqa @ W1r[l][128:256,:] ----
__global__ __launch_bounds__(128) void k_qagnn(unsigned short* __restrict__ h_q,
        const int* __restrict__ q_src, const int* __restrict__ q_dst,
        const float* __restrict__ beta_p, float* __restrict__ Qg,
        const float* __restrict__ W1r_l, float* __restrict__ cg2){
    int g = blockIdx.x, t = threadIdx.x;
    __shared__ float h[NQPG][132];
    __shared__ float e[EQPG], w[EQPG];
    __shared__ float inv[NQPG], mx[NQPG], den[NQPG];
    __shared__ int srcl[EQPG], dstl[EQPG], csr[EQPG];
    __shared__ int cnt[NQPG], off[NQPG], woff[NQPG];
    __shared__ float part[128];
    float beta = beta_p[0];
    for (int idx=t; idx<NQPG*128; idx+=128){
        int n = idx>>7, d = idx&127;
        h[n][d] = bf2f(h_q[(size_t)(g*NQPG+n)*128 + d]);
    }
    if (t<NQPG){ cnt[t]=0; mx[t]=0.f; den[t]=0.f; }
    __syncthreads();
    { int n=t>>3, c=t&7; float s=0;
      for (int d=c*16; d<c*16+16; d++){ float v=h[n][d]; s+=v*v; }
      part[t]=s; }
    __syncthreads();
    if (t<NQPG){ float s=0; for(int c=0;c<8;c++) s+=part[t*8+c]; inv[t]=rsqrtf(s+1e-24f); }
    __syncthreads();
    { int eidx = g*EQPG + t;
      int s = q_src[eidx] - g*NQPG, d = q_dst[eidx] - g*NQPG;
      srcl[t]=s; dstl[t]=d;
      float dot=0;
      for (int k=0;k<128;k++) dot += h[s][k]*h[d][k];
      e[t] = beta*dot*inv[s]*inv[d];
      atomicAdd(&cnt[d],1); }
    __syncthreads();
    if (t==0){ int o=0; for(int i=0;i<NQPG;i++){ off[i]=o; o+=cnt[i]; } }
    __syncthreads();
    if (t<NQPG){ woff[t]=off[t];
        if (cnt[t] > 0){
            float mm=-1e30f, dd=0.f;
            for (int j=0;j<EQPG;j++) if (dstl[j]==t) mm = fmaxf(mm, e[j]);
            for (int j=0;j<EQPG;j++) if (dstl[j]==t) dd += __expf(e[j]-mm);
            mx[t]=mm; den[t]=dd;
        } }
    __syncthreads();
    { int d = dstl[t];
      float dd = den[d];
      w[t] = dd > 0.f ? __expf(e[t]-mx[d]) / dd : 0.f;
      int pos = atomicAdd(&woff[d],1);
      csr[pos]=t; }
    __syncthreads();
    float aggr=0.f;
    { int d = t;
      for (int n=0;n<NQPG;n++){
          float acc=0.f;
          int o=off[n], c=cnt[n];
          for (int j=o;j<o+c;j++){ int ei=csr[j]; acc += w[ei]*h[srcl[ei]][d]; }
          h_q[(size_t)(g*NQPG+n)*128 + d] = f2bf(acc);
          aggr += acc;
      }
    }
    __syncthreads();
    part[t] = aggr*aggr;
    h[0][t] = aggr;
    __syncthreads();
    for (int s2=64; s2>0; s2>>=1){
        if (t<s2) part[t]+=part[t+s2];
        __syncthreads();
    }
    if (t==0) Qg[g]=part[0];
    float accc = 0.f;
    for (int k=0;k<128;k++) accc += h[0][k] * W1r_l[(128+k)*128 + t];
    cg2[g*128+t] = accc;
}

// ---- data-graph AGNN: 2 blocks per graph (node halves), csr-ordered edges,
//      no-max softmax with per-node local denominator (no atomics) ----
__global__ __launch_bounds__(1024) void k_gagnn(const unsigned short* __restrict__ h_g,
        const float* __restrict__ nrm2, const float* __restrict__ Qg,
        const unsigned short* __restrict__ csrc_g, const unsigned short* __restrict__ cdst_g,
        const int* __restrict__ off_g, const float* __restrict__ beta_p,
        unsigned short* __restrict__ aout){
    int b = blockIdx.x, g = b>>1, half = b&1;
    int t = threadIdx.x;
    int wave = t>>6, lane = t&63, sub = lane>>4, sl = lane&15;
    __shared__ float e_loc[EPG];
    __shared__ unsigned short ssrc[EPG];
    __shared__ float inv[NPG];
    __shared__ int offc[258];
    float beta = beta_p[0];
    float Q = Qg[g];
    int gbase = g*NPG;
    size_t ebase = (size_t)g*EPG;
    int nb0 = half*256;
    for (int n=t;n<NPG;n+=1024) inv[n] = rsqrtf(nrm2[gbase+n] + Q + 1e-24f);
    if (t < 256) offc[t] = off_g[g*NPG + nb0 + t];
    if (t == 256) offc[256] = (half ? EPG : off_g[g*NPG + 256]);
    __syncthreads();
    int ebeg = offc[0], eend = offc[256];
    int ecount = eend - ebeg;
    for (int j=t;j<ecount;j+=1024) ssrc[j] = csrc_g[ebase + ebeg + j];
    __syncthreads();
    // phase A: edge logits -> exp, 16 lanes per edge
    for (int j = wave*4 + sub; j < ecount; j += 64){
        int s = ssrc[j];
        int d = cdst_g[ebase + ebeg + j];
        uint4 us = *(const uint4*)(h_g + (size_t)(gbase+s)*128 + sl*8);
        uint4 ud = *(const uint4*)(h_g + (size_t)(gbase+d)*128 + sl*8);
        float v = dot8(us, ud);
        v += __shfl_xor(v,1); v += __shfl_xor(v,2);
        v += __shfl_xor(v,4); v += __shfl_xor(v,8);
        if (sl==0) e_loc[j] = __expf(beta * (v + Q) * inv[s]*inv[d]);
    }
    __syncthreads();
    // phase B: 16 lanes per node; in-edges contiguous; local denominator
    for (int nl = wave*4 + sub; nl < 256; nl += 64){
        int o = offc[nl] - ebeg;
        int c = offc[nl+1] - offc[nl];
        uint4 ov;
        if (c > 0){
            float wsum = 0.f;
            float a0=0,a1=0,a2=0,a3=0,a4=0,a5=0,a6=0,a7=0;
            for (int j=o;j<o+c;j++){
                float wg = e_loc[j];
                int s = ssrc[j];
                uint4 us = *(const uint4*)(h_g + (size_t)(gbase+s)*128 + sl*8);
                wsum += wg;
                a0 = fmaf(wg, bf2f((unsigned short)(us.x&0xffff)), a0);
                a1 = fmaf(wg, bf2f((unsigned short)(us.x>>16)),   a1);
                a2 = fmaf(wg, bf2f((unsigned short)(us.y&0xffff)), a2);
                a3 = fmaf(wg, bf2f((unsigned short)(us.y>>16)),   a3);
                a4 = fmaf(wg, bf2f((unsigned short)(us.z&0xffff)), a4);
                a5 = fmaf(wg, bf2f((unsigned short)(us.z>>16)),   a5);
                a6 = fmaf(wg, bf2f((unsigned short)(us.w&0xffff)), a6);
                a7 = fmaf(wg, bf2f((unsigned short)(us.w>>16)),   a7);
            }
            float iw = __frcp_rn(wsum);
            ov.x = (unsigned int)f2bf(a0*iw) | ((unsigned int)f2bf(a1*iw)<<16);
            ov.y = (unsigned int)f2bf(a2*iw) | ((unsigned int)f2bf(a3*iw)<<16);
            ov.z = (unsigned int)f2bf(a4*iw) | ((unsigned int)f2bf(a5*iw)<<16);
            ov.w = (unsigned int)f2bf(a6*iw) | ((unsigned int)f2bf(a7*iw)<<16);
        } else {
            ov.x=0; ov.y=0; ov.z=0; ov.w=0;
        }
        *(uint4*)(aout + (size_t)(gbase+nb0+nl)*128 + sl*8) = ov;
    }
}

// ---- persistent fused MLP: one block per graph, weights staged in LDS ----
#define SMEM_MLP (3*128*136*2)
__global__ __launch_bounds__(512, 2) void k_mlp_p(const unsigned short* __restrict__ A,
        const unsigned short* __restrict__ W1t, const float* __restrict__ b1,
        const float* __restrict__ cg2, const float* __restrict__ degf,
        const unsigned short* __restrict__ W2t, const float* __restrict__ b2,
        unsigned short* __restrict__ out, float* __restrict__ nrm2){
    extern __shared__ __align__(16) char smem[];
    unsigned short* W1s = (unsigned short*)smem;       // 128 x 136
    unsigned short* W2s = W1s + 128*136;
    unsigned short* h1  = W2s + 128*136;
    int t = threadIdx.x;
    int g = blockIdx.x;
    #pragma unroll
    for (int p=0;p<4;p++){
        int flat = p*4096 + t*8;
        int n = flat>>7, k = flat&127;
        *(uint4*)(W1s + n*136 + k) = *(const uint4*)(W1t + n*128 + k);
        *(uint4*)(W2s + n*136 + k) = *(const uint4*)(W2t + n*128 + k);
    }
    __syncthreads();
    int wave = t>>6, lane = t&63, quad = lane>>4, l16 = lane&15;
    const float* cg = cg2 + (size_t)g*128;
    short8 af[4];
    {
        int wrow = g*512 + wave*16;
        #pragma unroll
        for (int ks=0;ks<4;ks++)
            af[ks] = *(const short8*)(A + (size_t)(wrow+l16)*128 + ks*32 + quad*8);
    }
    for (int it=0; it<4; it++){
        int wrow = g*512 + it*128 + wave*16;
        floatx4 acc[8];
        #pragma unroll
        for (int t8=0;t8<8;t8++){
            #pragma unroll
            for (int r=0;r<4;r++) acc[t8][r]=0.f;
        }
        #pragma unroll
        for (int ks=0;ks<4;ks++){
            int koff = ks*32 + quad*8;
            #pragma unroll
            for (int t8=0;t8<8;t8++){
                short8 b = *(const short8*)(W1s + (t8*16+l16)*136 + koff);
                acc[t8] = __builtin_amdgcn_mfma_f32_16x16x32_bf16(af[ks], b, acc[t8], 0,0,0);
            }
        }
        float dg[4];
        #pragma unroll
        for (int r=0;r<4;r++) dg[r] = degf[wrow + quad*4 + r];
        #pragma unroll
        for (int t8=0;t8<8;t8++){
            int col = t8*16 + l16;
            float bv = b1[col];
            float cv = cg[col];
            #pragma unroll
            for (int r=0;r<4;r++){
                float v = acc[t8][r] + bv + dg[r]*cv;
                v = v > 0.f ? v : 0.f;
                h1[(wave*16 + quad*4 + r)*136 + col] = f2bf(v);
            }
        }
        __syncthreads();
        short8 afn[4];
        if (it < 3){
            int wrow_n = g*512 + (it+1)*128 + wave*16;
            #pragma unroll
            for (int ks=0;ks<4;ks++)
                afn[ks] = *(const short8*)(A + (size_t)(wrow_n+l16)*128 + ks*32 + quad*8);
        }
        short8 hf[4];
        #pragma unroll
        for (int ks=0;ks<4;ks++) hf[ks] = *(const short8*)(h1 + (wave*16+l16)*136 + ks*32 + quad*8);
        floatx4 acc2[8];
        #pragma unroll
        for (int t8=0;t8<8;t8++){
            #pragma unroll
            for (int r=0;r<4;r++) acc2[t8][r]=0.f;
        }
        #pragma unroll
        for (int ks=0;ks<4;ks++){
            int koff = ks*32 + quad*8;
            #pragma unroll
            for (int t8=0;t8<8;t8++){
                short8 b = *(const short8*)(W2s + (t8*16+l16)*136 + koff);
                acc2[t8] = __builtin_amdgcn_mfma_f32_16x16x32_bf16(hf[ks], b, acc2[t8], 0,0,0);
            }
        }
        float ss[4] = {0.f,0.f,0.f,0.f};
        #pragma unroll
        for (int t8=0;t8<8;t8++){
            int col = t8*16 + l16;
            float bv = b2[col];
            #pragma unroll
            for (int r=0;r<4;r++){
                float v = acc2[t8][r] + bv;
                out[(size_t)(wrow + quad*4 + r)*128 + col] = f2bf(v);
                ss[r] += v*v;
            }
        }
        #pragma unroll
        for (int r=0;r<4;r++){
            #pragma unroll
            for (int o=1;o<16;o<<=1) ss[r] += __shfl_xor(ss[r], o);
        }
        if (l16==0){
            #pragma unroll
            for (int r=0;r<4;r++) nrm2[wrow + quad*4 + r] = ss[r];
        }
        __syncthreads();
        #pragma unroll
        for (int ks=0;ks<4;ks++) af[ks] = afn[ks];
    }
}

// ---- fused per-graph sum + predictor ----
__global__ __launch_bounds__(512) void k_hgpred(const unsigned short* __restrict__ h_g,
        const float* __restrict__ Wp1, const float* __restrict__ bp1,
        const float* __restrict__ Wp2, const float* __restrict__ bp2,
        float* __restrict__ y){
    __shared__ float red[32][128];
    __shared__ float hsum[128];
    __shared__ float red2[128];
    int g = blockIdx.x, t = threadIdx.x;
    int c = t & 15, r0 = t >> 4;
    float s[8];
    #pragma unroll
    for (int k=0;k<8;k++) s[k]=0.f;
    for (int i=0;i<16;i++){
        int row = r0 + i*32;
        uint4 u = *(const uint4*)(h_g + (size_t)(g*NPG + row)*128 + c*8);
        s[0] += bf2f((unsigned short)(u.x&0xffff)); s[1] += bf2f((unsigned short)(u.x>>16));
        s[2] += bf2f((unsigned short)(u.y&0xffff)); s[3] += bf2f((unsigned short)(u.y>>16));
        s[4] += bf2f((unsigned short)(u.z&0xffff)); s[5] += bf2f((unsigned short)(u.z>>16));
        s[6] += bf2f((unsigned short)(u.w&0xffff)); s[7] += bf2f((unsigned short)(u.w>>16));
    }
    #pragma unroll
    for (int k=0;k<8;k++) red[r0][c*8+k] = s[k];
    __syncthreads();
    if (t < 128){
        float a = 0.f;
        #pragma unroll
        for (int r=0;r<32;r++) a += red[r][t];
        hsum[t] = a;
    }
    __syncthreads();
    if (t < 128){
        float acc = bp1[t];
        for (int k=0;k<128;k++) acc += hsum[k]*Wp1[k*128+t];
        acc = fmaxf(acc, 0.f);
        red2[t] = acc * Wp2[t];
    }
    __syncthreads();
    for (int s2=64; s2>0; s2>>=1){
        if (t<s2) red2[t]+=red2[t+s2];
        __syncthreads();
    }
    if (t==0) y[g] = red2[0] + bp2[0];
}

extern "C" void kernel_launch(void* const* d_in, const int* in_sizes, int n_in,
                              void* d_out, int out_size, void* d_ws, size_t ws_size,
                              hipStream_t stream) {
    const float* X    = (const float*)d_in[0];
    const float* X_q  = (const float*)d_in[1];
    const int* g_src = (const int*)d_in[2];
    const int* g_dst = (const int*)d_in[3];
    const int* q_src = (const int*)d_in[5];
    const int* q_dst = (const int*)d_in[6];
    const float* Wg   = (const float*)d_in[8];
    const float* bg   = (const float*)d_in[9];
    const float* Wq   = (const float*)d_in[10];
    const float* bq   = (const float*)d_in[11];
    const float* betas_g = (const float*)d_in[12];
    const float* betas_q = (const float*)d_in[13];
    const float* W1r  = (const float*)d_in[14];
    const float* b1r  = (const float*)d_in[15];
    const float* W2r  = (const float*)d_in[16];
    const float* b2r  = (const float*)d_in[17];
    const float* Wp1  = (const float*)d_in[18];
    const float* bp1  = (const float*)d_in[19];
    const float* Wp2  = (const float*)d_in[20];
    const float* bp2  = (const float*)d_in[21];

    uint8_t* w = (uint8_t*)d_ws;
    unsigned short* h_g  = (unsigned short*)w;    w += (size_t)NG*128*2;
    unsigned short* h_q  = (unsigned short*)w;    w += (size_t)NQ*128*2;
    unsigned short* aout = (unsigned short*)w;    w += (size_t)NG*128*2;
    float* nrm2  = (float*)w;                     w += (size_t)NG*4;
    float* degf  = (float*)w;                     w += (size_t)NG*4;
    float* Qg    = (float*)w;                     w += (size_t)B_*4*4;
    float* cg2   = (float*)w;                     w += (size_t)B_*128*4;
    unsigned short* WgT   = (unsigned short*)w;   w += 8192*2;
    unsigned short* WqT   = (unsigned short*)w;   w += 8192*2;
    unsigned short* W1aT  = (unsigned short*)w;   w += 2*16384*2;
    unsigned short* W2rT  = (unsigned short*)w;   w += 2*16384*2;
    unsigned short* csrc_g = (unsigned short*)w;  w += (size_t)B_*EPG*2;
    unsigned short* cdst_g = (unsigned short*)w;  w += (size_t)B_*EPG*2;
    int* off_g = (int*)w;                         w += (size_t)B_*NPG*4;

    static bool attr_done = false;
    if (!attr_done){
        hipFuncSetAttribute((const void*)k_mlp_p,
                            hipFuncAttributeMaxDynamicSharedMemorySize, SMEM_MLP);
        attr_done = true;
    }

    k_transpose<<<320,256,0,stream>>>(Wg,Wq,W1r,W2r,WgT,WqT,W1aT,W2rT);
    k_csr<<<B_,256,0,stream>>>(g_src,g_dst,csrc_g,cdst_g,off_g,degf);
    k_proj<<<NG/64,256,0,stream>>>(X,   WgT, bg, h_g, nrm2);
    k_proj<<<NQ/64,256,0,stream>>>(X_q, WqT, bq, h_q, nullptr);
    for (int l=0;l<L_;l++){
        k_qagnn<<<B_,128,0,stream>>>(h_q, q_src, q_dst, betas_q + l, Qg,
                                     W1r + l*32768, cg2);
        k_gagnn<<<2*B_,1024,0,stream>>>(h_g, nrm2, Qg, csrc_g, cdst_g, off_g,
                                        betas_g + l, aout);
        k_mlp_p<<<B_,512,SMEM_MLP,stream>>>(aout, W1aT + l*16384, b1r + l*128, cg2, degf,
                                            W2rT + l*16384, b2r + l*128, h_g, nrm2);
    }
    k_hgpred<<<B_,512,0,stream>>>(h_g, Wp1, bp1, Wp2, bp2, (float*)d_out);
}

// Round 12
// 371.776 us; speedup vs baseline: 1.1230x; 1.1230x over previous
//
#include <hip/hip_runtime.h>
#include <stdint.h>

#define B_   256
#define NPG  512
#define NG   131072
#define EPG  4096
#define NQPG 16
#define NQ   4096
#define EQPG 128
#define L_   2
#define HPITCH 136   // LDS row pitch in shorts (272 B, multiple of 16 B, staggers banks)

typedef __attribute__((ext_vector_type(8))) short short8;
typedef __attribute__((ext_vector_type(4))) float floatx4;

__device__ inline float bf2f(unsigned short u){
    union { unsigned int i; float f; } x; x.i = ((unsigned int)u) << 16; return x.f;
}
__device__ inline unsigned short f2bf(float f){
    union { float f; unsigned int i; } x; x.f = f;
    unsigned int r = x.i + 0x7fff + ((x.i >> 16) & 1);  // RNE
    return (unsigned short)(r >> 16);
}
__device__ inline float d2(unsigned int a, unsigned int b, float c){
#if __has_builtin(__builtin_amdgcn_fdot2_f32_bf16)
    typedef __attribute__((ext_vector_type(2))) __bf16 bf16x2;
    union { unsigned int u; bf16x2 v; } xa, xb;
    xa.u = a; xb.u = b;
    return __builtin_amdgcn_fdot2_f32_bf16(xa.v, xb.v, c, false);
#else
    union { unsigned int u; float f; } la, ha, lb, hb;
    la.u = a << 16; ha.u = a & 0xffff0000u;
    lb.u = b << 16; hb.u = b & 0xffff0000u;
    return fmaf(la.f, lb.f, fmaf(ha.f, hb.f, c));
#endif
}
__device__ inline float dot8(uint4 a, uint4 b){
    return d2(a.x,b.x, d2(a.y,b.y, d2(a.z,b.z, d2(a.w,b.w, 0.f))));
}

// ---- transpose weights (fp32 in) to [N][K] bf16 ----
__global__ void k_transpose(const float* Wg, const float* Wq,
                            const float* W1r, const float* W2r,
                            unsigned short* WgT, unsigned short* WqT,
                            unsigned short* W1aT, unsigned short* W2rT){
    int idx = blockIdx.x*256 + threadIdx.x;
    if (idx < 8192){
        int k = idx >> 7, n = idx & 127; WgT[n*64 + k] = f2bf(Wg[idx]);
    } else if (idx < 16384){
        int i = idx - 8192; int k = i>>7, n = i&127; WqT[n*64+k] = f2bf(Wq[i]);
    } else if (idx < 49152){
        int i = idx - 16384; int l = i >> 14; int j = i & 16383; int k = j>>7, n = j&127;
        W1aT[l*16384 + n*128 + k] = f2bf(W1r[l*32768 + j]);
    } else {
        int i = idx - 49152; int l = i >> 14; int j = i & 16383; int k = j>>7, n = j&127;
        W2rT[l*16384 + n*128 + k] = f2bf(W2r[i]);
    }
}

// ---- one-shot CSR build: csr-ordered src array + offsets + degf ----
__global__ __launch_bounds__(256) void k_csr(const int* __restrict__ g_src,
        const int* __restrict__ g_dst,
        unsigned short* __restrict__ csrc_g, int* __restrict__ off_g,
        float* __restrict__ degf){
    int g = blockIdx.x, t = threadIdx.x, lane = t & 63;
    __shared__ int cnt[NPG], woff[NPG];
    __shared__ int gscan[64];
    int gbase = g*NPG; size_t ebase = (size_t)g*EPG;
    for (int n=t;n<NPG;n+=256) cnt[n]=0;
    __syncthreads();
    for (int i=t;i<EPG;i+=256){
        int d = g_dst[ebase+i]-gbase;
        atomicAdd(&cnt[d],1);
    }
    __syncthreads();
    if (t < 64){
        int s=0;
        #pragma unroll
        for (int j=0;j<8;j++) s += cnt[t*8+j];
        int v=s;
        #pragma unroll
        for (int o=1;o<64;o<<=1){ int u=__shfl_up(v,o); if (lane>=o) v+=u; }
        gscan[t]=v;
    }
    __syncthreads();
    for (int n=t;n<NPG;n+=256){
        int grp=n>>3; int base = grp?gscan[grp-1]:0;
        for (int j=grp*8;j<n;j++) base+=cnt[j];
        off_g[g*NPG+n]=base; woff[n]=base;
        degf[gbase+n] = cnt[n]>0 ? 1.f : 0.f;
    }
    __syncthreads();
    for (int i=t;i<EPG;i+=256){
        int s = g_src[ebase+i]-gbase;
        int d = g_dst[ebase+i]-gbase;
        int pos = atomicAdd(&woff[d],1);
        csrc_g[ebase+pos]=(unsigned short)s;
    }
}

// ---- proj: out_bf16[M,128] = A_f32[M,64] @ WtT + bias ; optional row sumsq ----
__global__ __launch_bounds__(256) void k_proj(const float* __restrict__ A,
        const unsigned short* __restrict__ Wt, const float* __restrict__ bias,
        unsigned short* __restrict__ out, float* __restrict__ nrm2){
    const int K = 64;
    int wave = threadIdx.x >> 6, lane = threadIdx.x & 63;
    int quad = lane >> 4, l16 = lane & 15;
    int wrow = blockIdx.x*64 + wave*16;
    floatx4 acc[8];
    #pragma unroll
    for (int t=0;t<8;t++){
        #pragma unroll
        for (int r=0;r<4;r++) acc[t][r]=0.f;
    }
    #pragma unroll
    for (int ks = 0; ks < 2; ks++){
        int koff = ks*32 + quad*8;
        const float* ap = A + (size_t)(wrow+l16)*K + koff;
        short8 a;
        #pragma unroll
        for (int j=0;j<8;j++) a[j] = (short)f2bf(ap[j]);
        #pragma unroll
        for (int t=0;t<8;t++){
            short8 b = *(const short8*)(Wt + (size_t)(t*16+l16)*K + koff);
            acc[t] = __builtin_amdgcn_mfma_f32_16x16x32_bf16(a, b, acc[t], 0,0,0);
        }
    }
    float ss[4] = {0.f,0.f,0.f,0.f};
    #pragma unroll
    for (int t=0;t<8;t++){
        int col = t*16 + l16;
        float bv = bias[col];
        #pragma unroll
        for (int r=0;r<4;r++){
            float v = acc[t][r] + bv;
            out[(size_t)(wrow + quad*4 + r)*128 + col] = f2bf(v);
            ss[r] += v*v;
        }
    }
    if (nrm2){
        #pragma unroll
        for (int r=0;r<4;r++){
            #pragma unroll
            for (int o=1;o<16;o<<=1) ss[r] += __shfl_xor(ss[r], o);
        }
        if (l16==0){
            #pragma unroll
            for (int r=0;r<4;r++) nrm2[wrow + quad*4 + r] = ss[r];
        }
    }
}

// ---- query AGNN + Qg + fused cg2 = hqa @ W1r[l][128:256,:] ----
__global__ __launch_bounds__(128) void k_qagnn(unsigned short* __restrict__ h_q,
        const int* __restrict__ q_src, const int* __restrict__ q_dst,
        const float* __restrict__ beta_p, float* __restrict__ Qg,
        const float* __restrict__ W1r_l, float* __restrict__ cg2){
    int g = blockIdx.x, t = threadIdx.x;
    __shared__ float h[NQPG][132];
    __shared__ float e[EQPG], w[EQPG];
    __shared__ float inv[NQPG], mx[NQPG], den[NQPG];
    __shared__ int srcl[EQPG], dstl[EQPG], csr[EQPG];
    __shared__ int cnt[NQPG], off[NQPG], woff[NQPG];
    __shared__ float part[128];
    float beta = beta_p[0];
    for (int idx=t; idx<NQPG*128; idx+=128){
        int n = idx>>7, d = idx&127;
        h[n][d] = bf2f(h_q[(size_t)(g*NQPG+n)*128 + d]);
    }
    if (t<NQPG){ cnt[t]=0; mx[t]=0.f; den[t]=0.f; }
    __syncthreads();
    { int n=t>>3, c=t&7; float s=0;
      for (int d=c*16; d<c*16+16; d++){ float v=h[n][d]; s+=v*v; }
      part[t]=s; }
    __syncthreads();
    if (t<NQPG){ float s=0; for(int c=0;c<8;c++) s+=part[t*8+c]; inv[t]=rsqrtf(s+1e-24f); }
    __syncthreads();
    { int eidx = g*EQPG + t;
      int s = q_src[eidx] - g*NQPG, d = q_dst[eidx] - g*NQPG;
      srcl[t]=s; dstl[t]=d;
      float dot=0;
      for (int k=0;k<128;k++) dot += h[s][k]*h[d][k];
      e[t] = beta*dot*inv[s]*inv[d];
      atomicAdd(&cnt[d],1); }
    __syncthreads();
    if (t==0){ int o=0; for(int i=0;i<NQPG;i++){ off[i]=o; o+=cnt[i]; } }
    __syncthreads();
    if (t<NQPG){ woff[t]=off[t];
        if (cnt[t] > 0){
            float mm=-1e30f, dd=0.f;
            for (int j=0;j<EQPG;j++) if (dstl[j]==t) mm = fmaxf(mm, e[j]);
            for (int j=0;j<EQPG;j++) if (dstl[j]==t) dd += __expf(e[j]-mm);
            mx[t]=mm; den[t]=dd;
        } }
    __syncthreads();
    { int d = dstl[t];
      float dd = den[d];
      w[t] = dd > 0.f ? __expf(e[t]-mx[d]) / dd : 0.f;
      int pos = atomicAdd(&woff[d],1);
      csr[pos]=t; }
    __syncthreads();
    float aggr=0.f;
    { int d = t;
      for (int n=0;n<NQPG;n++){
          float acc=0.f;
          int o=off[n], c=cnt[n];
          for (int j=o;j<o+c;j++){ int ei=csr[j]; acc += w[ei]*h[srcl[ei]][d]; }
          h_q[(size_t)(g*NQPG+n)*128 + d] = f2bf(acc);
          aggr += acc;
      }
    }
    __syncthreads();
    part[t] = aggr*aggr;
    h[0][t] = aggr;
    __syncthreads();
    for (int s2=64; s2>0; s2>>=1){
        if (t<s2) part[t]+=part[t+s2];
        __syncthreads();
    }
    if (t==0) Qg[g]=part[0];
    float accc = 0.f;
    for (int k=0;k<128;k++) accc += h[0][k] * W1r_l[(128+k)*128 + t];
    cg2[g*128+t] = accc;
}

// ---- data-graph AGNN: one block per graph, full row slice staged in LDS,
//      node-centric fused logit+gather (src row read once from LDS per edge) ----
#define SMEM_GA 151568
__global__ __launch_bounds__(1024) void k_gagnn(const unsigned short* __restrict__ h_g,
        const float* __restrict__ nrm2, const float* __restrict__ Qg,
        const unsigned short* __restrict__ csrc_g, const int* __restrict__ off_g,
        const float* __restrict__ beta_p, unsigned short* __restrict__ aout){
    extern __shared__ __align__(16) char smem[];
    unsigned short* hrows = (unsigned short*)smem;             // 512 x HPITCH  (139264 B)
    float* inv            = (float*)(smem + 139264);           // 2048 B
    unsigned short* ssrc  = (unsigned short*)(smem + 141312);  // 8192 B
    int* offc             = (int*)(smem + 149504);             // 513*4 = 2052 B
    int g = blockIdx.x, t = threadIdx.x;
    int group = t >> 4, sl = t & 15;
    float beta = beta_p[0];
    float Q = Qg[g];
    int gbase = g*NPG;
    size_t ebase = (size_t)g*EPG;
    // stage rows: 512 rows x 16 uint4 (row pitch HPITCH shorts in LDS)
    for (int i=t; i<8192; i+=1024){
        int row = i >> 4, col = i & 15;
        *(uint4*)(hrows + row*HPITCH + col*8) =
            *(const uint4*)(h_g + (size_t)(gbase+row)*128 + col*8);
    }
    for (int n=t; n<NPG; n+=1024) inv[n] = rsqrtf(nrm2[gbase+n] + Q + 1e-24f);
    for (int i=t; i<EPG; i+=1024) ssrc[i] = csrc_g[ebase+i];
    for (int n=t; n<=NPG; n+=1024) offc[n] = (n<NPG) ? off_g[g*NPG+n] : EPG;
    __syncthreads();
    // node-centric: 64 groups of 16 lanes; 8 nodes/group
    for (int n = group; n < NPG; n += 64){
        int o = offc[n];
        int c = offc[n+1] - o;
        uint4 ov;
        if (c > 0){
            uint4 ud = *(const uint4*)(hrows + n*HPITCH + sl*8);
            float invn = inv[n];
            float wsum = 0.f;
            float a0=0,a1=0,a2=0,a3=0,a4=0,a5=0,a6=0,a7=0;
            for (int j=o; j<o+c; j++){
                int s = ssrc[j];
                uint4 us = *(const uint4*)(hrows + s*HPITCH + sl*8);
                float v = dot8(us, ud);
                v += __shfl_xor(v,1); v += __shfl_xor(v,2);
                v += __shfl_xor(v,4); v += __shfl_xor(v,8);
                float e = __expf(beta * (v + Q) * inv[s] * invn);
                wsum += e;
                a0 = fmaf(e, bf2f((unsigned short)(us.x&0xffff)), a0);
                a1 = fmaf(e, bf2f((unsigned short)(us.x>>16)),   a1);
                a2 = fmaf(e, bf2f((unsigned short)(us.y&0xffff)), a2);
                a3 = fmaf(e, bf2f((unsigned short)(us.y>>16)),   a3);
                a4 = fmaf(e, bf2f((unsigned short)(us.z&0xffff)), a4);
                a5 = fmaf(e, bf2f((unsigned short)(us.z>>16)),   a5);
                a6 = fmaf(e, bf2f((unsigned short)(us.w&0xffff)), a6);
                a7 = fmaf(e, bf2f((unsigned short)(us.w>>16)),   a7);
            }
            float iw = __frcp_rn(wsum);
            ov.x = (unsigned int)f2bf(a0*iw) | ((unsigned int)f2bf(a1*iw)<<16);
            ov.y = (unsigned int)f2bf(a2*iw) | ((unsigned int)f2bf(a3*iw)<<16);
            ov.z = (unsigned int)f2bf(a4*iw) | ((unsigned int)f2bf(a5*iw)<<16);
            ov.w = (unsigned int)f2bf(a6*iw) | ((unsigned int)f2bf(a7*iw)<<16);
        } else {
            ov.x=0; ov.y=0; ov.z=0; ov.w=0;
        }
        *(uint4*)(aout + (size_t)(gbase+n)*128 + sl*8) = ov;
    }
}

// ---- persistent fused MLP: one block per graph, weights staged in LDS ----
#define SMEM_MLP (3*128*136*2)
__global__ __launch_bounds__(512, 2) void k_mlp_p(const unsigned short* __restrict__ A,
        const unsigned short* __restrict__ W1t, const float* __restrict__ b1,
        const float* __restrict__ cg2, const float* __restrict__ degf,
        const unsigned short* __restrict__ W2t, const float* __restrict__ b2,
        unsigned short* __restrict__ out, float* __restrict__ nrm2){
    extern __shared__ __align__(16) char smem[];
    unsigned short* W1s = (unsigned short*)smem;       // 128 x 136
    unsigned short* W2s = W1s + 128*136;
    unsigned short* h1  = W2s + 128*136;
    int t = threadIdx.x;
    int g = blockIdx.x;
    #pragma unroll
    for (int p=0;p<4;p++){
        int flat = p*4096 + t*8;
        int n = flat>>7, k = flat&127;
        *(uint4*)(W1s + n*136 + k) = *(const uint4*)(W1t + n*128 + k);
        *(uint4*)(W2s + n*136 + k) = *(const uint4*)(W2t + n*128 + k);
    }
    __syncthreads();
    int wave = t>>6, lane = t&63, quad = lane>>4, l16 = lane&15;
    const float* cg = cg2 + (size_t)g*128;
    short8 af[4];
    {
        int wrow = g*512 + wave*16;
        #pragma unroll
        for (int ks=0;ks<4;ks++)
            af[ks] = *(const short8*)(A + (size_t)(wrow+l16)*128 + ks*32 + quad*8);
    }
    for (int it=0; it<4; it++){
        int wrow = g*512 + it*128 + wave*16;
        floatx4 acc[8];
        #pragma unroll
        for (int t8=0;t8<8;t8++){
            #pragma unroll
            for (int r=0;r<4;r++) acc[t8][r]=0.f;
        }
        #pragma unroll
        for (int ks=0;ks<4;ks++){
            int koff = ks*32 + quad*8;
            #pragma unroll
            for (int t8=0;t8<8;t8++){
                short8 b = *(const short8*)(W1s + (t8*16+l16)*136 + koff);
                acc[t8] = __builtin_amdgcn_mfma_f32_16x16x32_bf16(af[ks], b, acc[t8], 0,0,0);
            }
        }
        float dg[4];
        #pragma unroll
        for (int r=0;r<4;r++) dg[r] = degf[wrow + quad*4 + r];
        #pragma unroll
        for (int t8=0;t8<8;t8++){
            int col = t8*16 + l16;
            float bv = b1[col];
            float cv = cg[col];
            #pragma unroll
            for (int r=0;r<4;r++){
                float v = acc[t8][r] + bv + dg[r]*cv;
                v = v > 0.f ? v : 0.f;
                h1[(wave*16 + quad*4 + r)*136 + col] = f2bf(v);
            }
        }
        __syncthreads();
        short8 afn[4];
        if (it < 3){
            int wrow_n = g*512 + (it+1)*128 + wave*16;
            #pragma unroll
            for (int ks=0;ks<4;ks++)
                afn[ks] = *(const short8*)(A + (size_t)(wrow_n+l16)*128 + ks*32 + quad*8);
        }
        short8 hf[4];
        #pragma unroll
        for (int ks=0;ks<4;ks++) hf[ks] = *(const short8*)(h1 + (wave*16+l16)*136 + ks*32 + quad*8);
        floatx4 acc2[8];
        #pragma unroll
        for (int t8=0;t8<8;t8++){
            #pragma unroll
            for (int r=0;r<4;r++) acc2[t8][r]=0.f;
        }
        #pragma unroll
        for (int ks=0;ks<4;ks++){
            int koff = ks*32 + quad*8;
            #pragma unroll
            for (int t8=0;t8<8;t8++){
                short8 b = *(const short8*)(W2s + (t8*16+l16)*136 + koff);
                acc2[t8] = __builtin_amdgcn_mfma_f32_16x16x32_bf16(hf[ks], b, acc2[t8], 0,0,0);
            }
        }
        float ss[4] = {0.f,0.f,0.f,0.f};
        #pragma unroll
        for (int t8=0;t8<8;t8++){
            int col = t8*16 + l16;
            float bv = b2[col];
            #pragma unroll
            for (int r=0;r<4;r++){
                float v = acc2[t8][r] + bv;
                out[(size_t)(wrow + quad*4 + r)*128 + col] = f2bf(v);
                ss[r] += v*v;
            }
        }
        #pragma unroll
        for (int r=0;r<4;r++){
            #pragma unroll
            for (int o=1;o<16;o<<=1) ss[r] += __shfl_xor(ss[r], o);
        }
        if (l16==0){
            #pragma unroll
            for (int r=0;r<4;r++) nrm2[wrow + quad*4 + r] = ss[r];
        }
        __syncthreads();
        #pragma unroll
        for (int ks=0;ks<4;ks++) af[ks] = afn[ks];
    }
}

// ---- fused per-graph sum + predictor ----
__global__ __launch_bounds__(512) void k_hgpred(const unsigned short* __restrict__ h_g,
        const float* __restrict__ Wp1, const float* __restrict__ bp1,
        const float* __restrict__ Wp2, const float* __restrict__ bp2,
        float* __restrict__ y){
    __shared__ float red[32][128];
    __shared__ float hsum[128];
    __shared__ float red2[128];
    int g = blockIdx.x, t = threadIdx.x;
    int c = t & 15, r0 = t >> 4;
    float s[8];
    #pragma unroll
    for (int k=0;k<8;k++) s[k]=0.f;
    for (int i=0;i<16;i++){
        int row = r0 + i*32;
        uint4 u = *(const uint4*)(h_g + (size_t)(g*NPG + row)*128 + c*8);
        s[0] += bf2f((unsigned short)(u.x&0xffff)); s[1] += bf2f((unsigned short)(u.x>>16));
        s[2] += bf2f((unsigned short)(u.y&0xffff)); s[3] += bf2f((unsigned short)(u.y>>16));
        s[4] += bf2f((unsigned short)(u.z&0xffff)); s[5] += bf2f((unsigned short)(u.z>>16));
        s[6] += bf2f((unsigned short)(u.w&0xffff)); s[7] += bf2f((unsigned short)(u.w>>16));
    }
    #pragma unroll
    for (int k=0;k<8;k++) red[r0][c*8+k] = s[k];
    __syncthreads();
    if (t < 128){
        float a = 0.f;
        #pragma unroll
        for (int r=0;r<32;r++) a += red[r][t];
        hsum[t] = a;
    }
    __syncthreads();
    if (t < 128){
        float acc = bp1[t];
        for (int k=0;k<128;k++) acc += hsum[k]*Wp1[k*128+t];
        acc = fmaxf(acc, 0.f);
        red2[t] = acc * Wp2[t];
    }
    __syncthreads();
    for (int s2=64; s2>0; s2>>=1){
        if (t<s2) red2[t]+=red2[t+s2];
        __syncthreads();
    }
    if (t==0) y[g] = red2[0] + bp2[0];
}

extern "C" void kernel_launch(void* const* d_in, const int* in_sizes, int n_in,
                              void* d_out, int out_size, void* d_ws, size_t ws_size,
                              hipStream_t stream) {
    const float* X    = (const float*)d_in[0];
    const float* X_q  = (const float*)d_in[1];
    const int* g_src = (const int*)d_in[2];
    const int* g_dst = (const int*)d_in[3];
    const int* q_src = (const int*)d_in[5];
    const int* q_dst = (const int*)d_in[6];
    const float* Wg   = (const float*)d_in[8];
    const float* bg   = (const float*)d_in[9];
    const float* Wq   = (const float*)d_in[10];
    const float* bq   = (const float*)d_in[11];
    const float* betas_g = (const float*)d_in[12];
    const float* betas_q = (const float*)d_in[13];
    const float* W1r  = (const float*)d_in[14];
    const float* b1r  = (const float*)d_in[15];
    const float* W2r  = (const float*)d_in[16];
    const float* b2r  = (const float*)d_in[17];
    const float* Wp1  = (const float*)d_in[18];
    const float* bp1  = (const float*)d_in[19];
    const float* Wp2  = (const float*)d_in[20];
    const float* bp2  = (const float*)d_in[21];

    uint8_t* w = (uint8_t*)d_ws;
    unsigned short* h_g  = (unsigned short*)w;    w += (size_t)NG*128*2;
    unsigned short* h_q  = (unsigned short*)w;    w += (size_t)NQ*128*2;
    unsigned short* aout = (unsigned short*)w;    w += (size_t)NG*128*2;
    float* nrm2  = (float*)w;                     w += (size_t)NG*4;
    float* degf  = (float*)w;                     w += (size_t)NG*4;
    float* Qg    = (float*)w;                     w += (size_t)B_*4*4;
    float* cg2   = (float*)w;                     w += (size_t)B_*128*4;
    unsigned short* WgT   = (unsigned short*)w;   w += 8192*2;
    unsigned short* WqT   = (unsigned short*)w;   w += 8192*2;
    unsigned short* W1aT  = (unsigned short*)w;   w += 2*16384*2;
    unsigned short* W2rT  = (unsigned short*)w;   w += 2*16384*2;
    unsigned short* csrc_g = (unsigned short*)w;  w += (size_t)B_*EPG*2;
    int* off_g = (int*)w;                         w += (size_t)B_*NPG*4;

    static bool attr_done = false;
    if (!attr_done){
        hipFuncSetAttribute((const void*)k_mlp_p,
                            hipFuncAttributeMaxDynamicSharedMemorySize, SMEM_MLP);
        hipFuncSetAttribute((const void*)k_gagnn,
                            hipFuncAttributeMaxDynamicSharedMemorySize, SMEM_GA);
        attr_done = true;
    }

    k_transpose<<<320,256,0,stream>>>(Wg,Wq,W1r,W2r,WgT,WqT,W1aT,W2rT);
    k_csr<<<B_,256,0,stream>>>(g_src,g_dst,csrc_g,off_g,degf);
    k_proj<<<NG/64,256,0,stream>>>(X,   WgT, bg, h_g, nrm2);
    k_proj<<<NQ/64,256,0,stream>>>(X_q, WqT, bq, h_q, nullptr);
    for (int l=0;l<L_;l++){
        k_qagnn<<<B_,128,0,stream>>>(h_q, q_src, q_dst, betas_q + l, Qg,
                                     W1r + l*32768, cg2);
        k_gagnn<<<B_,1024,SMEM_GA,stream>>>(h_g, nrm2, Qg, csrc_g, off_g,
                                            betas_g + l, aout);
        k_mlp_p<<<B_,512,SMEM_MLP,stream>>>(aout, W1aT + l*16384, b1r + l*128, cg2, degf,
                                            W2rT + l*16384, b2r + l*128, h_g, nrm2);
    }
    k_hgpred<<<B_,512,0,stream>>>(h_g, Wp1, bp1, Wp2, bp2, (float*)d_out);
}